// Round 17
// baseline (99.806 us; speedup 1.0000x reference)
//
#include <hip/hip_runtime.h>
#include <hip/hip_bf16.h>

typedef __attribute__((ext_vector_type(8))) __bf16 bf16x8;
typedef __attribute__((ext_vector_type(8))) unsigned short ushort8;
typedef __attribute__((ext_vector_type(4))) float f32x4;

#define DEVFN static __device__ __forceinline__

constexpr int B_ = 4, N_ = 1024, H_ = 8, DH_ = 64, INNER_ = 512, QC_ = 1536;
constexpr int JS_ = 2;                            // attention j-split
constexpr float LA_ = 0.33f, LD_ = 0.33f, LG_ = 0.33f;
constexpr float SCALE2_ = 0.125f * 1.44269504088896f;   // 1/sqrt(64) * log2(e)
constexpr long OCP_STRIDE_ = (long)4096 * 512;   // per-js partial O (bf16 elems)
constexpr long LP_STRIDE_  = (long)4 * 8 * 1024; // per-js partial l (f32 elems)

DEVFN unsigned short f2b(float f){
  unsigned int u = __builtin_bit_cast(unsigned int, f);
  u += 0x7FFFu + ((u >> 16) & 1u);
  return (unsigned short)(u >> 16);
}
DEVFN float b2f(unsigned short s){
  unsigned int u = ((unsigned int)s) << 16;
  return __builtin_bit_cast(float, u);
}
DEVFN float fexp2(float x){   // 2^x, single v_exp_f32 (HW-interlocked)
  float r; asm("v_exp_f32 %0, %1" : "=v"(r) : "v"(x)); return r;
}
DEVFN unsigned int pack2(float lo, float hi){  // 2 x f32 -> packed bf16 (RNE)
  union { unsigned int u; __bf16 h[2]; } z;
  z.h[0] = (__bf16)lo; z.h[1] = (__bf16)hi;
  return z.u;
}

DEVFN f32x4 mfma16(bf16x8 a, bf16x8 b, f32x4 c){
  return __builtin_amdgcn_mfma_f32_16x16x32_bf16(a, b, c, 0, 0, 0);
}

DEVFN bf16x8 ldsb8(const unsigned short* p){ return *(const bf16x8*)p; }

// async global->LDS, 16B per lane; LDS dest is wave-uniform base + lane*16
DEVFN void gload16(const unsigned short* g, unsigned short* l){
  __builtin_amdgcn_global_load_lds(
      (const __attribute__((address_space(1))) unsigned int*)g,
      (__attribute__((address_space(3))) unsigned int*)l, 16, 0, 0);
}

// LDS-only workgroup barrier (no vmcnt drain).
DEVFN void lds_barrier(){
  __builtin_amdgcn_sched_barrier(0);
  asm volatile("s_waitcnt lgkmcnt(0)\n\ts_barrier" ::: "memory");
  __builtin_amdgcn_sched_barrier(0);
}

// LESSONS LOG:
//  r6: 64-lane same-address shared atomicAdd serializes ~64x (use __ballot).
//  r8: XCD block swizzle null/negative — working set is L3-resident.
//  r8: 256-block grids = 1 wave/SIMD leave every stall exposed (G1).
//  r10: padded LDS rows de-conflict; XOR on top re-conflicts. Pad OR swizzle.
//  r11/r12: barrier vmcnt-drain removal NEUTRAL — occupancy covers the drain.
//  r13: JS 2->4 regressed (fixed costs); r14: 2-deep reg prefetch NEUTRAL.
//  r15: QB=128 + kf-hoist WIN (-1.7us). r16: DMA staging REGRESSED (+4.8us):
//       dbuf LDS 27.6->41.2KB cut residency 5->3 blocks/CU. Check LDS
//       occupancy BEFORE adding buffers. Reverted to r15 structure.
//  r17 (this round): softmax VALU thinning — attn is VALU-bound (~7.5
//       ops/elem): pre-scale Q in gemm0 epilogue, f32 mbias add instead of
//       mask bit-tests, hoist V-frags across q-groups. ~4.5 ops/elem.

// wave-0 ballot-based mask-encoding detect. t<64 == wave 0 exactly.
DEVFN int detect_enc_w0(const unsigned char* m8, const int* m32, const float* mf,
                        int t, int* fsh){
  if (t < 64){
    unsigned char a = m8[t];
    int bb = m32[t];
    float c = mf[t];
    unsigned long long bad0 = __ballot(a > 1);
    unsigned long long one0 = __ballot(a == 1);
    unsigned long long bad1 = __ballot(bb != 0 && bb != 1);
    unsigned long long one1 = __ballot(bb == 1);
    unsigned long long bad2 = __ballot(c != 0.0f && c != 1.0f);
    unsigned long long one2 = __ballot(c == 1.0f);
    if (t == 0){
      int f = 0;
      if (bad0 == 0ull && __popcll(one0) > 42) f = 0;
      else if (bad1 == 0ull && __popcll(one1) > 42) f = 1;
      else if (bad2 == 0ull && __popcll(one2) > 42) f = 2;
      *fsh = f;
    }
  }
  __syncthreads();
  return *fsh;
}

// ---------- fused prep: mask(+mbias) | cvt x | transpose Wqkv | transpose Wout ----------
__global__ void prep_k(const unsigned char* __restrict__ m8, const int* __restrict__ m32,
                       const float* __restrict__ mf, unsigned char* __restrict__ mv,
                       float* __restrict__ mbias,
                       const float* __restrict__ x, unsigned short* __restrict__ xb,
                       const float* __restrict__ Wq, unsigned short* __restrict__ WqT,
                       const float* __restrict__ Wo, unsigned short* __restrict__ WoT)
{
  const int bid = blockIdx.x, t = threadIdx.x;
  if (bid < 16){
    __shared__ int fsh;
    int f = detect_enc_w0(m8, m32, mf, t, &fsh);
    int i = bid * 256 + t;
    unsigned char v;
    if (f == 0) v = (m8[i] != 0);
    else if (f == 1) v = (m32[i] != 0);
    else v = (mf[i] != 0.0f);
    mv[i] = v;
    mbias[i] = v ? 0.0f : -3e38f;        // softmax additive key-mask (r17)
  } else if (bid < 2064){
    int i = (bid - 16) * 256 + t;
    float4 v = ((const float4*)x)[i];
    ushort4 o = { f2b(v.x), f2b(v.y), f2b(v.z), f2b(v.w) };
    ((ushort4*)xb)[i] = o;
  } else {
    const float* W; unsigned short* Wt; int K, Nn, bx, by;
    if (bid < 2832){ W = Wq; Wt = WqT; K = 512; Nn = 1536; int r = bid - 2064; bx = r % 48; by = r / 48; }
    else           { W = Wo; Wt = WoT; K = 512; Nn = 512;  int r = bid - 2832; bx = r % 16; by = r / 16; }
    __shared__ float tt[32][33];
    int nb = bx * 32, kb = by * 32;
    int tx = t & 31, ty = t >> 5;
    #pragma unroll
    for (int i = 0; i < 32; i += 8)
      tt[ty + i][tx] = W[(long)(kb + ty + i) * Nn + nb + tx];
    __syncthreads();
    #pragma unroll
    for (int i = 0; i < 32; i += 8)
      Wt[(long)(nb + ty + i) * K + kb + tx] = f2b(tt[tx][ty + i]);
  }
}

// ---------- bf16 MFMA GEMM, 2-phase double-buffered + LDS XOR swizzle ----------
// MODE 0: Cout(bf16) = acc, Q columns pre-scaled by SCALE2_ (r17);
//         V-columns additionally scattered into VtOut
// MODE 1: Cout(bf16) = acc + LA*(sum_js O_js)/(sum_js l_js)  (attn combine)
// MODE 2: Cout(f32)  = acc + Cin[col] (bias)
template<int MODE, int BM, int BN>
__global__ __launch_bounds__(256)
void gemm_bt_k(const unsigned short* __restrict__ A, const unsigned short* __restrict__ Bt,
               const float* __restrict__ Cin, void* __restrict__ Cout,
               const unsigned short* __restrict__ Op, const float* __restrict__ Lp,
               unsigned short* __restrict__ VtOut,
               int M, int Nn, int K, long azs, long bzs)
{
  constexpr int BK = 64;
  constexpr int WM = BM / 2, WN = BN / 2, MR = WM / 16, NR = WN / 16;
  __shared__ __attribute__((aligned(16))) unsigned short As[2][BM * BK];
  __shared__ __attribute__((aligned(16))) unsigned short Bs[2][BN * BK];
  const int bm = blockIdx.x * BM, bn = blockIdx.y * BN, z = blockIdx.z;
  const unsigned short* Ap = A + (long)z * azs;
  const unsigned short* Bp = Bt + (long)z * bzs;
  const int tid = threadIdx.x, w = tid >> 6, lane = tid & 63;
  const int l15 = lane & 15, lg = lane >> 4;
  const int wr = w >> 1, wc = w & 1;
  const int srow = lane >> 3;
  const int sk0 = ((lane & 7) ^ srow) * 8;            // pre-swizzled source chunk
  const int rk0 = (lg ^ (l15 & 7)) * 8;               // swizzled read slot, k<32
  const int rk1 = ((lg + 4) ^ (l15 & 7)) * 8;         // swizzled read slot, k>=32

  f32x4 acc[MR][NR] = {};

  for (int kk = 0;;){
    if (kk == 0){
      #pragma unroll
      for (int i = 0; i < BM / 32; i++){
        int r0 = i * 32 + w * 8;
        gload16(Ap + (long)(bm + r0 + srow) * K + sk0, &As[0][r0 * BK]);
      }
      #pragma unroll
      for (int i = 0; i < BN / 32; i++){
        int r0 = i * 32 + w * 8;
        gload16(Bp + (long)(bn + r0 + srow) * K + sk0, &Bs[0][r0 * BK]);
      }
      __syncthreads();   // drains vmcnt: tile0 visible (required for DMA)
    }
    int cur = (kk / BK) & 1;
    if (kk + BK < K){
      #pragma unroll
      for (int i = 0; i < BM / 32; i++){
        int r0 = i * 32 + w * 8;
        gload16(Ap + (long)(bm + r0 + srow) * K + (kk + BK) + sk0, &As[cur ^ 1][r0 * BK]);
      }
      #pragma unroll
      for (int i = 0; i < BN / 32; i++){
        int r0 = i * 32 + w * 8;
        gload16(Bp + (long)(bn + r0 + srow) * K + (kk + BK) + sk0, &Bs[cur ^ 1][r0 * BK]);
      }
    }
    bf16x8 af[MR][2], bf[NR][2];
    #pragma unroll
    for (int m = 0; m < MR; m++){
      const unsigned short* p = &As[cur][(wr * WM + m * 16 + l15) * BK];
      af[m][0] = ldsb8(p + rk0); af[m][1] = ldsb8(p + rk1);
    }
    #pragma unroll
    for (int n = 0; n < NR; n++){
      const unsigned short* p = &Bs[cur][(wc * WN + n * 16 + l15) * BK];
      bf[n][0] = ldsb8(p + rk0); bf[n][1] = ldsb8(p + rk1);
    }
    #pragma unroll
    for (int m = 0; m < MR; m++)
      #pragma unroll
      for (int n = 0; n < NR; n++){
        acc[m][n] = mfma16(af[m][0], bf[n][0], acc[m][n]);
        acc[m][n] = mfma16(af[m][1], bf[n][1], acc[m][n]);
      }
    kk += BK;
    if (kk >= K) break;
    __syncthreads();
  }

  #pragma unroll
  for (int m = 0; m < MR; m++)
    #pragma unroll
    for (int n = 0; n < NR; n++){
      int row0 = bm + wr * WM + m * 16 + lg * 4;
      int col = bn + wc * WN + n * 16 + l15;
      if (MODE == 0){
        int hm = col % 192;
        float qscl = (hm < 64) ? SCALE2_ : 1.0f;   // pre-scale Q for attn (r17)
        ushort4 o;
        unsigned short* op = (unsigned short*)&o;
        #pragma unroll
        for (int r = 0; r < 4; r++){
          op[r] = f2b(acc[m][n][r] * qscl);
          ((unsigned short*)Cout)[(long)(row0 + r) * Nn + col] = op[r];
        }
        if (hm >= 128){
          int bb = row0 >> 10, j0 = row0 & (N_ - 1);
          int hd = (col / 192) * 64 + (hm - 128);
          *(ushort4*)(VtOut + ((long)bb * INNER_ + hd) * N_ + j0) = o;
        }
      } else if (MODE == 1){
        #pragma unroll
        for (int r = 0; r < 4; r++){
          int row = row0 + r;
          float v = acc[m][n][r];
          long obase = ((long)z * N_ + row) * INNER_ + col;
          long lbase = ((long)z * H_ + (col >> 6)) * N_ + row;
          float o = 0.f, l = 0.f;
          #pragma unroll
          for (int js = 0; js < JS_; js++){
            o += b2f(Op[js * OCP_STRIDE_ + obase]);
            l += Lp[js * LP_STRIDE_ + lbase];
          }
          v += LA_ * o / l;
          ((unsigned short*)Cout)[((long)z * N_ + row) * Nn + col] = f2b(v);
        }
      } else {
        #pragma unroll
        for (int r = 0; r < 4; r++)
          ((float*)Cout)[(long)(row0 + r) * Nn + col] = acc[m][n][r] + Cin[col];
      }
    }
}

// ---------- fused: streaming attention partial | Madd build ----------
// blocks [0,512): attention (QB=128, 2 q-groups/wave, JS=2);
// blocks [512,4608): Madd (heterogeneous overlap — r9).
// Attention LDS: [64][72] padded rows, natural chunks, reg staging (r15/r16).
// Softmax: Q pre-scaled, f32 mbias add, V-frags hoisted (r17).
__global__ __launch_bounds__(256, 3)
void attn_madd_k(const unsigned short* __restrict__ QKV, const unsigned short* __restrict__ Vt,
                 const unsigned char* __restrict__ mv, const float* __restrict__ mbias,
                 unsigned short* __restrict__ Ocp, float* __restrict__ Lp,
                 const unsigned char* __restrict__ m8, const int* __restrict__ m32,
                 const float* __restrict__ mf,
                 const float* __restrict__ adj, const float* __restrict__ dist,
                 unsigned short* __restrict__ Madd)
{
  __shared__ __attribute__((aligned(16))) unsigned short Ks[64][72];      // [j][k]
  __shared__ __attribute__((aligned(16))) unsigned short Vs[64][72];      // [d][j]
  __shared__ __attribute__((aligned(16))) unsigned short Ps[4][16][72];   // [q][k]
  const int bid = blockIdx.x, tid = threadIdx.x;

  if (bid >= 512){
    // ---- Madd branch ----
    int f = detect_enc_w0(m8, m32, mf, tid, (int*)&Ps[0][0][0]);
    long i = (long)(bid - 512) * 256 + tid;
    long e = i * 4;
    int b = (int)(e >> 20);
    int rem = (int)(e & (long)(N_ * N_ - 1));
    int row = rem >> 10, col0 = rem & (N_ - 1);
    float4 a = ((const float4*)adj)[i];
    float4 d = ((const float4*)dist)[i];
    bool mi, mc[4];
    if (f == 0){
      mi = m8[b * N_ + row] != 0;
      unsigned int pk = *(const unsigned int*)(m8 + b * N_ + col0);
      #pragma unroll
      for (int r = 0; r < 4; r++) mc[r] = ((pk >> (8 * r)) & 255u) != 0;
    } else if (f == 1){
      mi = m32[b * N_ + row] != 0;
      #pragma unroll
      for (int r = 0; r < 4; r++) mc[r] = m32[b * N_ + col0 + r] != 0;
    } else {
      mi = mf[b * N_ + row] != 0.0f;
      #pragma unroll
      for (int r = 0; r < 4; r++) mc[r] = mf[b * N_ + col0 + r] != 0.0f;
    }
    float va[4] = {a.x, a.y, a.z, a.w};
    float vd[4] = {d.x, d.y, d.z, d.w};
    ushort4 o;
    unsigned short* op = (unsigned short*)&o;
    #pragma unroll
    for (int r = 0; r < 4; r++){
      bool m2 = mi && mc[r];
      float v = m2 ? (LG_ * va[r] + LD_ * __expf(-vd[r])) : 0.0f;
      op[r] = f2b(v);
    }
    ((ushort4*)Madd)[i] = o;
    return;
  }

  // ---- attention branch (swapped QK^T, no-max softmax, QB=128, JS=2) ----
  const int qb = (bid & 7) * 128, h = (bid >> 3) & 7;
  const int zc = bid >> 6;                // [0, 4*JS_)
  const int b = zc & 3, js = zc >> 2;     // js in [0, JS_)
  const int w = tid >> 6, lane = tid & 63;
  const int l15 = lane & 15, lg = lane >> 4;

  // two q-groups per wave: rows qb + w*32 + qg*16 + l15  (Q pre-scaled)
  bf16x8 qf[2][2];
  bool rv[2];
  #pragma unroll
  for (int qg = 0; qg < 2; qg++){
    const long qr = (long)(b * N_ + qb + w * 32 + qg * 16 + l15) * QC_ + h * 192;
    qf[qg][0] = *(const bf16x8*)(QKV + qr + lg * 8);
    qf[qg][1] = *(const bf16x8*)(QKV + qr + 32 + lg * 8);
    rv[qg] = mv[b * N_ + qb + w * 32 + qg * 16 + l15] != 0;
  }

  float l_run[2] = {0.f, 0.f};
  f32x4 acc[2][4] = {};

  const unsigned short* Vbase = Vt + ((long)b * INNER_ + h * DH_) * N_;
  const unsigned short* Kbase = QKV + (long)b * N_ * QC_ + h * 192 + 64;
  const int kr0 = tid >> 3, kr1 = kr0 + 32;
  const int ko = (tid & 7) * 8;                  // natural chunk (write & global)
  const int jb0 = js * (N_ / JS_);
  constexpr int NT = N_ / JS_ / 64;              // j-tiles per block (8 at JS=2)

  // prologue: load tile 0 into registers (T14 issue-early/write-late)
  ushort8 kreg0, kreg1, vreg0, vreg1;
  {
    kreg0 = *(const ushort8*)(Kbase + (long)(jb0 + kr0) * QC_ + ko);
    kreg1 = *(const ushort8*)(Kbase + (long)(jb0 + kr1) * QC_ + ko);
    vreg0 = *(const ushort8*)(Vbase + (long)kr0 * N_ + jb0 + ko);
    vreg1 = *(const ushort8*)(Vbase + (long)kr1 * N_ + jb0 + ko);
  }

  for (int jt = 0; jt < NT; jt++){
    const int jbase = jb0 + jt * 64;
    lds_barrier();                        // prev iter's LDS reads complete
    *(ushort8*)&Ks[kr0][ko] = kreg0;
    *(ushort8*)&Ks[kr1][ko] = kreg1;
    *(ushort8*)&Vs[kr0][ko] = vreg0;
    *(ushort8*)&Vs[kr1][ko] = vreg1;
    if (jt < NT - 1){
      const int jn = jbase + 64;
      kreg0 = *(const ushort8*)(Kbase + (long)(jn + kr0) * QC_ + ko);
      kreg1 = *(const ushort8*)(Kbase + (long)(jn + kr1) * QC_ + ko);
      vreg0 = *(const ushort8*)(Vbase + (long)kr0 * N_ + jn + ko);
      vreg1 = *(const ushort8*)(Vbase + (long)kr1 * N_ + jn + ko);
    }
    lds_barrier();                        // K/V tile visible

    // hoist K and V fragments + mbias once per tile (reused by both q-groups)
    bf16x8 kf[4][2], vf[4][2];
    float mbv[4][4];
    #pragma unroll
    for (int ct = 0; ct < 4; ct++){
      kf[ct][0] = ldsb8(&Ks[ct * 16 + l15][lg * 8]);
      kf[ct][1] = ldsb8(&Ks[ct * 16 + l15][32 + lg * 8]);
      vf[ct][0] = ldsb8(&Vs[ct * 16 + l15][lg * 8]);
      vf[ct][1] = ldsb8(&Vs[ct * 16 + l15][32 + lg * 8]);
      float4 mb = *(const float4*)(mbias + b * N_ + jbase + ct * 16 + lg * 4);
      mbv[ct][0] = mb.x; mbv[ct][1] = mb.y; mbv[ct][2] = mb.z; mbv[ct][3] = mb.w;
    }

    #pragma unroll
    for (int qg = 0; qg < 2; qg++){
      // S^T = K Q^T : lane holds key = ct*16 + lg*4 + r, q = l15
      f32x4 s[4];
      __builtin_amdgcn_s_setprio(1);
      #pragma unroll
      for (int ct = 0; ct < 4; ct++){
        f32x4 zz = {};
        zz = mfma16(kf[ct][0], qf[qg][0], zz);
        zz = mfma16(kf[ct][1], qf[qg][1], zz);
        s[ct] = zz;
      }
      __builtin_amdgcn_s_setprio(0);

      // no-max softmax: Q pre-scaled, key-mask is additive f32 bias (r17).
      // invalid row -> sv=0 (uniform); invalid key -> +(-3e38) -> exp2 = 0.
      float tsum = 0.f;
      unsigned int pw[4][2];
      #pragma unroll
      for (int ct = 0; ct < 4; ct++){
        float pv[4];
        #pragma unroll
        for (int r = 0; r < 4; r++){
          float sv = s[ct][r] + mbv[ct][r];
          if (!rv[qg]) sv = 0.0f;
          float pp = fexp2(sv);
          tsum += pp;
          pv[r] = pp;
        }
        pw[ct][0] = pack2(pv[0], pv[1]);
        pw[ct][1] = pack2(pv[2], pv[3]);
      }
      tsum += __shfl_xor(tsum, 16);
      tsum += __shfl_xor(tsum, 32);
      l_run[qg] += tsum;

      // Ps reused across qg: wave-local wait ensures prior reads landed
      asm volatile("s_waitcnt lgkmcnt(0)" ::: "memory");
      __builtin_amdgcn_sched_barrier(0);
      #pragma unroll
      for (int ct = 0; ct < 4; ct++)
        #pragma unroll
        for (int p2 = 0; p2 < 2; p2++){
          int klo = ct * 16 + lg * 4 + 2 * p2;
          *(unsigned int*)&Ps[w][l15][klo] = pw[ct][p2];
        }
      asm volatile("s_waitcnt lgkmcnt(0)" ::: "memory");
      __builtin_amdgcn_sched_barrier(0);

      bf16x8 pf0 = ldsb8(&Ps[w][l15][lg * 8]);
      bf16x8 pf1 = ldsb8(&Ps[w][l15][32 + lg * 8]);
      __builtin_amdgcn_s_setprio(1);
      #pragma unroll
      for (int ct = 0; ct < 4; ct++){
        acc[qg][ct] = mfma16(pf0, vf[ct][0], acc[qg][ct]);
        acc[qg][ct] = mfma16(pf1, vf[ct][1], acc[qg][ct]);
      }
      __builtin_amdgcn_s_setprio(0);
    }
  }

  // write unnormalized partial O (bf16) and partial l (f32)
  #pragma unroll
  for (int qg = 0; qg < 2; qg++){
    #pragma unroll
    for (int r = 0; r < 4; r++){
      long orow = (long)js * (OCP_STRIDE_ / INNER_) + b * N_ + qb + w * 32 + qg * 16 + lg * 4 + r;
      #pragma unroll
      for (int ct = 0; ct < 4; ct++)
        Ocp[orow * INNER_ + h * DH_ + ct * 16 + l15] = f2b(acc[qg][ct][r]);
    }
    if (lg == 0)
      Lp[(long)js * LP_STRIDE_ + ((long)b * H_ + h) * N_ + qb + w * 32 + qg * 16 + l15] = l_run[qg];
  }
}

extern "C" void kernel_launch(void* const* d_in, const int* in_sizes, int n_in,
                              void* d_out, int out_size, void* d_ws, size_t ws_size,
                              hipStream_t stream)
{
  const float* x    = (const float*)d_in[0];
  const void*  msk  = d_in[1];
  const float* adj  = (const float*)d_in[2];
  const float* dst  = (const float*)d_in[3];
  const float* wqkv = (const float*)d_in[4];
  const float* wout = (const float*)d_in[5];
  const float* bout = (const float*)d_in[6];
  float* out = (float*)d_out;

  char* p = (char*)d_ws;
  unsigned short* QKV  = (unsigned short*)p;  p += (long)4096 * 1536 * 2;
  unsigned short* Xb   = (unsigned short*)p;  p += (long)4096 * 512 * 2;
  unsigned short* WqT  = (unsigned short*)p;  p += (long)1536 * 512 * 2;
  unsigned short* WoT  = (unsigned short*)p;  p += (long)512 * 512 * 2;
  unsigned short* Vt   = (unsigned short*)p;  p += (long)4 * 512 * 1024 * 2;
  unsigned short* Madd = (unsigned short*)p;  p += (long)4 * 1024 * 1024 * 2;
  unsigned short* Ocp  = (unsigned short*)p;  p += (long)JS_ * OCP_STRIDE_ * 2;
  float*          Lp   = (float*)p;           p += (long)JS_ * LP_STRIDE_ * 4;
  unsigned short* OcB  = (unsigned short*)p;  p += (long)4096 * 512 * 2;
  unsigned char*  mv   = (unsigned char*)p;   p += 4096;
  float*          mbias = (float*)p;          p += 4096 * 4;

  prep_k<<<3088, 256, 0, stream>>>((const unsigned char*)msk, (const int*)msk,
                                   (const float*)msk, mv, mbias, x, Xb, wqkv, WqT, wout, WoT);
  gemm_bt_k<0, 128, 64><<<dim3(32, 24, 1), 256, 0, stream>>>(
      Xb, WqT, nullptr, QKV, nullptr, nullptr, Vt, 4096, 1536, 512, 0, 0);
  attn_madd_k<<<4608, 256, 0, stream>>>(QKV, Vt, mv, mbias, Ocp, Lp,
                                        (const unsigned char*)msk, (const int*)msk,
                                        (const float*)msk, adj, dst, Madd);
  gemm_bt_k<1, 64, 64><<<dim3(16, 8, 4), 256, 0, stream>>>(
      Madd, Vt, nullptr, OcB, Ocp, Lp, nullptr, 1024, 512, 1024,
      (long)1024 * 1024, (long)512 * 1024);
  gemm_bt_k<2, 64, 64><<<dim3(64, 8, 1), 256, 0, stream>>>(
      OcB, WoT, bout, out, nullptr, nullptr, nullptr, 4096, 512, 512, 0, 0);
}

// Round 18
// 77.068 us; speedup vs baseline: 1.2950x; 1.2950x over previous
//
#include <hip/hip_runtime.h>
#include <hip/hip_bf16.h>

typedef __attribute__((ext_vector_type(8))) __bf16 bf16x8;
typedef __attribute__((ext_vector_type(8))) unsigned short ushort8;
typedef __attribute__((ext_vector_type(4))) float f32x4;

#define DEVFN static __device__ __forceinline__

constexpr int B_ = 4, N_ = 1024, H_ = 8, DH_ = 64, INNER_ = 512, QC_ = 1536;
constexpr int JS_ = 2;                            // attention j-split
constexpr float LA_ = 0.33f, LD_ = 0.33f, LG_ = 0.33f;
constexpr float SCALE2_ = 0.125f * 1.44269504088896f;   // 1/sqrt(64) * log2(e)
constexpr long OCP_STRIDE_ = (long)4096 * 512;   // per-js partial O (bf16 elems)
constexpr long LP_STRIDE_  = (long)4 * 8 * 1024; // per-js partial l (f32 elems)

DEVFN unsigned short f2b(float f){
  unsigned int u = __builtin_bit_cast(unsigned int, f);
  u += 0x7FFFu + ((u >> 16) & 1u);
  return (unsigned short)(u >> 16);
}
DEVFN float b2f(unsigned short s){
  unsigned int u = ((unsigned int)s) << 16;
  return __builtin_bit_cast(float, u);
}
DEVFN float fexp2(float x){   // 2^x, single v_exp_f32 (HW-interlocked)
  float r; asm("v_exp_f32 %0, %1" : "=v"(r) : "v"(x)); return r;
}
DEVFN unsigned int pack2(float lo, float hi){  // 2 x f32 -> packed bf16 (RNE)
  union { unsigned int u; __bf16 h[2]; } z;
  z.h[0] = (__bf16)lo; z.h[1] = (__bf16)hi;
  return z.u;
}

DEVFN f32x4 mfma16(bf16x8 a, bf16x8 b, f32x4 c){
  return __builtin_amdgcn_mfma_f32_16x16x32_bf16(a, b, c, 0, 0, 0);
}

DEVFN bf16x8 ldsb8(const unsigned short* p){ return *(const bf16x8*)p; }

// async global->LDS, 16B per lane; LDS dest is wave-uniform base + lane*16
DEVFN void gload16(const unsigned short* g, unsigned short* l){
  __builtin_amdgcn_global_load_lds(
      (const __attribute__((address_space(1))) unsigned int*)g,
      (__attribute__((address_space(3))) unsigned int*)l, 16, 0, 0);
}

// LDS-only workgroup barrier (no vmcnt drain).
DEVFN void lds_barrier(){
  __builtin_amdgcn_sched_barrier(0);
  asm volatile("s_waitcnt lgkmcnt(0)\n\ts_barrier" ::: "memory");
  __builtin_amdgcn_sched_barrier(0);
}

// LESSONS LOG:
//  r6: 64-lane same-address shared atomicAdd serializes ~64x (use __ballot).
//  r8: XCD block swizzle null/negative — working set is L3-resident.
//  r8: 256-block grids = 1 wave/SIMD leave every stall exposed (G1).
//  r10: padded LDS rows de-conflict; XOR on top re-conflicts. Pad OR swizzle.
//  r11/r12: barrier vmcnt-drain removal NEUTRAL — occupancy covers the drain.
//  r13: JS 2->4 regressed (fixed costs); r14: 2-deep reg prefetch NEUTRAL.
//  r15: QB=128 + kf-hoist WIN (70.7us best). r16: DMA dbuf LDS growth cut
//       residency 5->3 — regressed. Check LDS occupancy before adding buffers.
//  r17: vf-hoist(+32reg)+mbv(+12) under launch_bounds(256,3) SPILLED to
//       scratch: +90MB r/w traffic, 67us kernel. Register hoists need VGPR
//       headroom; drop the min-waves spec and keep live set lean.
//  r18 (this round): r15 structure + Q-prescale (free) + mbias add (+8 reg),
//       vf inline, plain launch_bounds(256).

// wave-0 ballot-based mask-encoding detect. t<64 == wave 0 exactly.
DEVFN int detect_enc_w0(const unsigned char* m8, const int* m32, const float* mf,
                        int t, int* fsh){
  if (t < 64){
    unsigned char a = m8[t];
    int bb = m32[t];
    float c = mf[t];
    unsigned long long bad0 = __ballot(a > 1);
    unsigned long long one0 = __ballot(a == 1);
    unsigned long long bad1 = __ballot(bb != 0 && bb != 1);
    unsigned long long one1 = __ballot(bb == 1);
    unsigned long long bad2 = __ballot(c != 0.0f && c != 1.0f);
    unsigned long long one2 = __ballot(c == 1.0f);
    if (t == 0){
      int f = 0;
      if (bad0 == 0ull && __popcll(one0) > 42) f = 0;
      else if (bad1 == 0ull && __popcll(one1) > 42) f = 1;
      else if (bad2 == 0ull && __popcll(one2) > 42) f = 2;
      *fsh = f;
    }
  }
  __syncthreads();
  return *fsh;
}

// ---------- fused prep: mask(+mbias) | cvt x | transpose Wqkv | transpose Wout ----------
__global__ void prep_k(const unsigned char* __restrict__ m8, const int* __restrict__ m32,
                       const float* __restrict__ mf, unsigned char* __restrict__ mv,
                       float* __restrict__ mbias,
                       const float* __restrict__ x, unsigned short* __restrict__ xb,
                       const float* __restrict__ Wq, unsigned short* __restrict__ WqT,
                       const float* __restrict__ Wo, unsigned short* __restrict__ WoT)
{
  const int bid = blockIdx.x, t = threadIdx.x;
  if (bid < 16){
    __shared__ int fsh;
    int f = detect_enc_w0(m8, m32, mf, t, &fsh);
    int i = bid * 256 + t;
    unsigned char v;
    if (f == 0) v = (m8[i] != 0);
    else if (f == 1) v = (m32[i] != 0);
    else v = (mf[i] != 0.0f);
    mv[i] = v;
    mbias[i] = v ? 0.0f : -3e38f;        // softmax additive key-mask (r17)
  } else if (bid < 2064){
    int i = (bid - 16) * 256 + t;
    float4 v = ((const float4*)x)[i];
    ushort4 o = { f2b(v.x), f2b(v.y), f2b(v.z), f2b(v.w) };
    ((ushort4*)xb)[i] = o;
  } else {
    const float* W; unsigned short* Wt; int K, Nn, bx, by;
    if (bid < 2832){ W = Wq; Wt = WqT; K = 512; Nn = 1536; int r = bid - 2064; bx = r % 48; by = r / 48; }
    else           { W = Wo; Wt = WoT; K = 512; Nn = 512;  int r = bid - 2832; bx = r % 16; by = r / 16; }
    __shared__ float tt[32][33];
    int nb = bx * 32, kb = by * 32;
    int tx = t & 31, ty = t >> 5;
    #pragma unroll
    for (int i = 0; i < 32; i += 8)
      tt[ty + i][tx] = W[(long)(kb + ty + i) * Nn + nb + tx];
    __syncthreads();
    #pragma unroll
    for (int i = 0; i < 32; i += 8)
      Wt[(long)(nb + ty + i) * K + kb + tx] = f2b(tt[tx][ty + i]);
  }
}

// ---------- bf16 MFMA GEMM, 2-phase double-buffered + LDS XOR swizzle ----------
// MODE 0: Cout(bf16) = acc, Q columns pre-scaled by SCALE2_ (r17);
//         V-columns additionally scattered into VtOut
// MODE 1: Cout(bf16) = acc + LA*(sum_js O_js)/(sum_js l_js)  (attn combine)
// MODE 2: Cout(f32)  = acc + Cin[col] (bias)
template<int MODE, int BM, int BN>
__global__ __launch_bounds__(256)
void gemm_bt_k(const unsigned short* __restrict__ A, const unsigned short* __restrict__ Bt,
               const float* __restrict__ Cin, void* __restrict__ Cout,
               const unsigned short* __restrict__ Op, const float* __restrict__ Lp,
               unsigned short* __restrict__ VtOut,
               int M, int Nn, int K, long azs, long bzs)
{
  constexpr int BK = 64;
  constexpr int WM = BM / 2, WN = BN / 2, MR = WM / 16, NR = WN / 16;
  __shared__ __attribute__((aligned(16))) unsigned short As[2][BM * BK];
  __shared__ __attribute__((aligned(16))) unsigned short Bs[2][BN * BK];
  const int bm = blockIdx.x * BM, bn = blockIdx.y * BN, z = blockIdx.z;
  const unsigned short* Ap = A + (long)z * azs;
  const unsigned short* Bp = Bt + (long)z * bzs;
  const int tid = threadIdx.x, w = tid >> 6, lane = tid & 63;
  const int l15 = lane & 15, lg = lane >> 4;
  const int wr = w >> 1, wc = w & 1;
  const int srow = lane >> 3;
  const int sk0 = ((lane & 7) ^ srow) * 8;            // pre-swizzled source chunk
  const int rk0 = (lg ^ (l15 & 7)) * 8;               // swizzled read slot, k<32
  const int rk1 = ((lg + 4) ^ (l15 & 7)) * 8;         // swizzled read slot, k>=32

  f32x4 acc[MR][NR] = {};

  for (int kk = 0;;){
    if (kk == 0){
      #pragma unroll
      for (int i = 0; i < BM / 32; i++){
        int r0 = i * 32 + w * 8;
        gload16(Ap + (long)(bm + r0 + srow) * K + sk0, &As[0][r0 * BK]);
      }
      #pragma unroll
      for (int i = 0; i < BN / 32; i++){
        int r0 = i * 32 + w * 8;
        gload16(Bp + (long)(bn + r0 + srow) * K + sk0, &Bs[0][r0 * BK]);
      }
      __syncthreads();   // drains vmcnt: tile0 visible (required for DMA)
    }
    int cur = (kk / BK) & 1;
    if (kk + BK < K){
      #pragma unroll
      for (int i = 0; i < BM / 32; i++){
        int r0 = i * 32 + w * 8;
        gload16(Ap + (long)(bm + r0 + srow) * K + (kk + BK) + sk0, &As[cur ^ 1][r0 * BK]);
      }
      #pragma unroll
      for (int i = 0; i < BN / 32; i++){
        int r0 = i * 32 + w * 8;
        gload16(Bp + (long)(bn + r0 + srow) * K + (kk + BK) + sk0, &Bs[cur ^ 1][r0 * BK]);
      }
    }
    bf16x8 af[MR][2], bf[NR][2];
    #pragma unroll
    for (int m = 0; m < MR; m++){
      const unsigned short* p = &As[cur][(wr * WM + m * 16 + l15) * BK];
      af[m][0] = ldsb8(p + rk0); af[m][1] = ldsb8(p + rk1);
    }
    #pragma unroll
    for (int n = 0; n < NR; n++){
      const unsigned short* p = &Bs[cur][(wc * WN + n * 16 + l15) * BK];
      bf[n][0] = ldsb8(p + rk0); bf[n][1] = ldsb8(p + rk1);
    }
    #pragma unroll
    for (int m = 0; m < MR; m++)
      #pragma unroll
      for (int n = 0; n < NR; n++){
        acc[m][n] = mfma16(af[m][0], bf[n][0], acc[m][n]);
        acc[m][n] = mfma16(af[m][1], bf[n][1], acc[m][n]);
      }
    kk += BK;
    if (kk >= K) break;
    __syncthreads();
  }

  #pragma unroll
  for (int m = 0; m < MR; m++)
    #pragma unroll
    for (int n = 0; n < NR; n++){
      int row0 = bm + wr * WM + m * 16 + lg * 4;
      int col = bn + wc * WN + n * 16 + l15;
      if (MODE == 0){
        int hm = col % 192;
        float qscl = (hm < 64) ? SCALE2_ : 1.0f;   // pre-scale Q for attn (r17)
        ushort4 o;
        unsigned short* op = (unsigned short*)&o;
        #pragma unroll
        for (int r = 0; r < 4; r++){
          op[r] = f2b(acc[m][n][r] * qscl);
          ((unsigned short*)Cout)[(long)(row0 + r) * Nn + col] = op[r];
        }
        if (hm >= 128){
          int bb = row0 >> 10, j0 = row0 & (N_ - 1);
          int hd = (col / 192) * 64 + (hm - 128);
          *(ushort4*)(VtOut + ((long)bb * INNER_ + hd) * N_ + j0) = o;
        }
      } else if (MODE == 1){
        #pragma unroll
        for (int r = 0; r < 4; r++){
          int row = row0 + r;
          float v = acc[m][n][r];
          long obase = ((long)z * N_ + row) * INNER_ + col;
          long lbase = ((long)z * H_ + (col >> 6)) * N_ + row;
          float o = 0.f, l = 0.f;
          #pragma unroll
          for (int js = 0; js < JS_; js++){
            o += b2f(Op[js * OCP_STRIDE_ + obase]);
            l += Lp[js * LP_STRIDE_ + lbase];
          }
          v += LA_ * o / l;
          ((unsigned short*)Cout)[((long)z * N_ + row) * Nn + col] = f2b(v);
        }
      } else {
        #pragma unroll
        for (int r = 0; r < 4; r++)
          ((float*)Cout)[(long)(row0 + r) * Nn + col] = acc[m][n][r] + Cin[col];
      }
    }
}

// ---------- fused: streaming attention partial | Madd build ----------
// blocks [0,512): attention (QB=128, 2 q-groups/wave, JS=2);
// blocks [512,4608): Madd (heterogeneous overlap — r9).
// Attention LDS: [64][72] padded rows, natural chunks, reg staging (r15).
// Softmax: Q pre-scaled, f32 mbias add; kf+mbias hoisted, vf INLINE (r18:
// keep live set under the spill threshold).
__global__ __launch_bounds__(256)
void attn_madd_k(const unsigned short* __restrict__ QKV, const unsigned short* __restrict__ Vt,
                 const unsigned char* __restrict__ mv, const float* __restrict__ mbias,
                 unsigned short* __restrict__ Ocp, float* __restrict__ Lp,
                 const unsigned char* __restrict__ m8, const int* __restrict__ m32,
                 const float* __restrict__ mf,
                 const float* __restrict__ adj, const float* __restrict__ dist,
                 unsigned short* __restrict__ Madd)
{
  __shared__ __attribute__((aligned(16))) unsigned short Ks[64][72];      // [j][k]
  __shared__ __attribute__((aligned(16))) unsigned short Vs[64][72];      // [d][j]
  __shared__ __attribute__((aligned(16))) unsigned short Ps[4][16][72];   // [q][k]
  const int bid = blockIdx.x, tid = threadIdx.x;

  if (bid >= 512){
    // ---- Madd branch ----
    int f = detect_enc_w0(m8, m32, mf, tid, (int*)&Ps[0][0][0]);
    long i = (long)(bid - 512) * 256 + tid;
    long e = i * 4;
    int b = (int)(e >> 20);
    int rem = (int)(e & (long)(N_ * N_ - 1));
    int row = rem >> 10, col0 = rem & (N_ - 1);
    float4 a = ((const float4*)adj)[i];
    float4 d = ((const float4*)dist)[i];
    bool mi, mc[4];
    if (f == 0){
      mi = m8[b * N_ + row] != 0;
      unsigned int pk = *(const unsigned int*)(m8 + b * N_ + col0);
      #pragma unroll
      for (int r = 0; r < 4; r++) mc[r] = ((pk >> (8 * r)) & 255u) != 0;
    } else if (f == 1){
      mi = m32[b * N_ + row] != 0;
      #pragma unroll
      for (int r = 0; r < 4; r++) mc[r] = m32[b * N_ + col0 + r] != 0;
    } else {
      mi = mf[b * N_ + row] != 0.0f;
      #pragma unroll
      for (int r = 0; r < 4; r++) mc[r] = mf[b * N_ + col0 + r] != 0.0f;
    }
    float va[4] = {a.x, a.y, a.z, a.w};
    float vd[4] = {d.x, d.y, d.z, d.w};
    ushort4 o;
    unsigned short* op = (unsigned short*)&o;
    #pragma unroll
    for (int r = 0; r < 4; r++){
      bool m2 = mi && mc[r];
      float v = m2 ? (LG_ * va[r] + LD_ * __expf(-vd[r])) : 0.0f;
      op[r] = f2b(v);
    }
    ((ushort4*)Madd)[i] = o;
    return;
  }

  // ---- attention branch (swapped QK^T, no-max softmax, QB=128, JS=2) ----
  const int qb = (bid & 7) * 128, h = (bid >> 3) & 7;
  const int zc = bid >> 6;                // [0, 4*JS_)
  const int b = zc & 3, js = zc >> 2;     // js in [0, JS_)
  const int w = tid >> 6, lane = tid & 63;
  const int l15 = lane & 15, lg = lane >> 4;

  // two q-groups per wave: rows qb + w*32 + qg*16 + l15  (Q pre-scaled)
  bf16x8 qf[2][2];
  bool rv[2];
  #pragma unroll
  for (int qg = 0; qg < 2; qg++){
    const long qr = (long)(b * N_ + qb + w * 32 + qg * 16 + l15) * QC_ + h * 192;
    qf[qg][0] = *(const bf16x8*)(QKV + qr + lg * 8);
    qf[qg][1] = *(const bf16x8*)(QKV + qr + 32 + lg * 8);
    rv[qg] = mv[b * N_ + qb + w * 32 + qg * 16 + l15] != 0;
  }

  float l_run[2] = {0.f, 0.f};
  f32x4 acc[2][4] = {};

  const unsigned short* Vbase = Vt + ((long)b * INNER_ + h * DH_) * N_;
  const unsigned short* Kbase = QKV + (long)b * N_ * QC_ + h * 192 + 64;
  const int kr0 = tid >> 3, kr1 = kr0 + 32;
  const int ko = (tid & 7) * 8;                  // natural chunk (write & global)
  const int jb0 = js * (N_ / JS_);
  constexpr int NT = N_ / JS_ / 64;              // j-tiles per block (8 at JS=2)

  // prologue: load tile 0 into registers (T14 issue-early/write-late)
  ushort8 kreg0, kreg1, vreg0, vreg1;
  {
    kreg0 = *(const ushort8*)(Kbase + (long)(jb0 + kr0) * QC_ + ko);
    kreg1 = *(const ushort8*)(Kbase + (long)(jb0 + kr1) * QC_ + ko);
    vreg0 = *(const ushort8*)(Vbase + (long)kr0 * N_ + jb0 + ko);
    vreg1 = *(const ushort8*)(Vbase + (long)kr1 * N_ + jb0 + ko);
  }

  for (int jt = 0; jt < NT; jt++){
    const int jbase = jb0 + jt * 64;
    lds_barrier();                        // prev iter's LDS reads complete
    *(ushort8*)&Ks[kr0][ko] = kreg0;
    *(ushort8*)&Ks[kr1][ko] = kreg1;
    *(ushort8*)&Vs[kr0][ko] = vreg0;
    *(ushort8*)&Vs[kr1][ko] = vreg1;
    if (jt < NT - 1){
      const int jn = jbase + 64;
      kreg0 = *(const ushort8*)(Kbase + (long)(jn + kr0) * QC_ + ko);
      kreg1 = *(const ushort8*)(Kbase + (long)(jn + kr1) * QC_ + ko);
      vreg0 = *(const ushort8*)(Vbase + (long)kr0 * N_ + jn + ko);
      vreg1 = *(const ushort8*)(Vbase + (long)kr1 * N_ + jn + ko);
    }
    lds_barrier();                        // K/V tile visible

    // hoist K fragments + mbias once per tile (reused by both q-groups);
    // V-frags stay inline in PV (r18: spill avoidance)
    bf16x8 kf[4][2];
    float mbv[4][4];
    #pragma unroll
    for (int ct = 0; ct < 4; ct++){
      kf[ct][0] = ldsb8(&Ks[ct * 16 + l15][lg * 8]);
      kf[ct][1] = ldsb8(&Ks[ct * 16 + l15][32 + lg * 8]);
      float4 mb = *(const float4*)(mbias + b * N_ + jbase + ct * 16 + lg * 4);
      mbv[ct][0] = mb.x; mbv[ct][1] = mb.y; mbv[ct][2] = mb.z; mbv[ct][3] = mb.w;
    }

    #pragma unroll
    for (int qg = 0; qg < 2; qg++){
      // S^T = K Q^T : lane holds key = ct*16 + lg*4 + r, q = l15
      f32x4 s[4];
      __builtin_amdgcn_s_setprio(1);
      #pragma unroll
      for (int ct = 0; ct < 4; ct++){
        f32x4 zz = {};
        zz = mfma16(kf[ct][0], qf[qg][0], zz);
        zz = mfma16(kf[ct][1], qf[qg][1], zz);
        s[ct] = zz;
      }
      __builtin_amdgcn_s_setprio(0);

      // no-max softmax: Q pre-scaled, key-mask is additive f32 bias (r17).
      float tsum = 0.f;
      unsigned int pw[4][2];
      #pragma unroll
      for (int ct = 0; ct < 4; ct++){
        float pv[4];
        #pragma unroll
        for (int r = 0; r < 4; r++){
          float sv = s[ct][r] + mbv[ct][r];
          if (!rv[qg]) sv = 0.0f;
          float pp = fexp2(sv);
          tsum += pp;
          pv[r] = pp;
        }
        pw[ct][0] = pack2(pv[0], pv[1]);
        pw[ct][1] = pack2(pv[2], pv[3]);
      }
      tsum += __shfl_xor(tsum, 16);
      tsum += __shfl_xor(tsum, 32);
      l_run[qg] += tsum;

      // Ps reused across qg: wave-local wait ensures prior reads landed
      asm volatile("s_waitcnt lgkmcnt(0)" ::: "memory");
      __builtin_amdgcn_sched_barrier(0);
      #pragma unroll
      for (int ct = 0; ct < 4; ct++)
        #pragma unroll
        for (int p2 = 0; p2 < 2; p2++){
          int klo = ct * 16 + lg * 4 + 2 * p2;
          *(unsigned int*)&Ps[w][l15][klo] = pw[ct][p2];
        }
      asm volatile("s_waitcnt lgkmcnt(0)" ::: "memory");
      __builtin_amdgcn_sched_barrier(0);

      bf16x8 pf0 = ldsb8(&Ps[w][l15][lg * 8]);
      bf16x8 pf1 = ldsb8(&Ps[w][l15][32 + lg * 8]);
      __builtin_amdgcn_s_setprio(1);
      #pragma unroll
      for (int ct = 0; ct < 4; ct++){
        bf16x8 v0 = ldsb8(&Vs[ct * 16 + l15][lg * 8]);
        bf16x8 v1 = ldsb8(&Vs[ct * 16 + l15][32 + lg * 8]);
        acc[qg][ct] = mfma16(pf0, v0, acc[qg][ct]);
        acc[qg][ct] = mfma16(pf1, v1, acc[qg][ct]);
      }
      __builtin_amdgcn_s_setprio(0);
    }
  }

  // write unnormalized partial O (bf16) and partial l (f32)
  #pragma unroll
  for (int qg = 0; qg < 2; qg++){
    #pragma unroll
    for (int r = 0; r < 4; r++){
      long orow = (long)js * (OCP_STRIDE_ / INNER_) + b * N_ + qb + w * 32 + qg * 16 + lg * 4 + r;
      #pragma unroll
      for (int ct = 0; ct < 4; ct++)
        Ocp[orow * INNER_ + h * DH_ + ct * 16 + l15] = f2b(acc[qg][ct][r]);
    }
    if (lg == 0)
      Lp[(long)js * LP_STRIDE_ + ((long)b * H_ + h) * N_ + qb + w * 32 + qg * 16 + l15] = l_run[qg];
  }
}

extern "C" void kernel_launch(void* const* d_in, const int* in_sizes, int n_in,
                              void* d_out, int out_size, void* d_ws, size_t ws_size,
                              hipStream_t stream)
{
  const float* x    = (const float*)d_in[0];
  const void*  msk  = d_in[1];
  const float* adj  = (const float*)d_in[2];
  const float* dst  = (const float*)d_in[3];
  const float* wqkv = (const float*)d_in[4];
  const float* wout = (const float*)d_in[5];
  const float* bout = (const float*)d_in[6];
  float* out = (float*)d_out;

  char* p = (char*)d_ws;
  unsigned short* QKV  = (unsigned short*)p;  p += (long)4096 * 1536 * 2;
  unsigned short* Xb   = (unsigned short*)p;  p += (long)4096 * 512 * 2;
  unsigned short* WqT  = (unsigned short*)p;  p += (long)1536 * 512 * 2;
  unsigned short* WoT  = (unsigned short*)p;  p += (long)512 * 512 * 2;
  unsigned short* Vt   = (unsigned short*)p;  p += (long)4 * 512 * 1024 * 2;
  unsigned short* Madd = (unsigned short*)p;  p += (long)4 * 1024 * 1024 * 2;
  unsigned short* Ocp  = (unsigned short*)p;  p += (long)JS_ * OCP_STRIDE_ * 2;
  float*          Lp   = (float*)p;           p += (long)JS_ * LP_STRIDE_ * 4;
  unsigned short* OcB  = (unsigned short*)p;  p += (long)4096 * 512 * 2;
  unsigned char*  mv   = (unsigned char*)p;   p += 4096;
  float*          mbias = (float*)p;          p += 4096 * 4;

  prep_k<<<3088, 256, 0, stream>>>((const unsigned char*)msk, (const int*)msk,
                                   (const float*)msk, mv, mbias, x, Xb, wqkv, WqT, wout, WoT);
  gemm_bt_k<0, 128, 64><<<dim3(32, 24, 1), 256, 0, stream>>>(
      Xb, WqT, nullptr, QKV, nullptr, nullptr, Vt, 4096, 1536, 512, 0, 0);
  attn_madd_k<<<4608, 256, 0, stream>>>(QKV, Vt, mv, mbias, Ocp, Lp,
                                        (const unsigned char*)msk, (const int*)msk,
                                        (const float*)msk, adj, dst, Madd);
  gemm_bt_k<1, 64, 64><<<dim3(16, 8, 4), 256, 0, stream>>>(
      Madd, Vt, nullptr, OcB, Ocp, Lp, nullptr, 1024, 512, 1024,
      (long)1024 * 1024, (long)512 * 1024);
  gemm_bt_k<2, 64, 64><<<dim3(64, 8, 1), 256, 0, stream>>>(
      OcB, WoT, bout, out, nullptr, nullptr, nullptr, 4096, 512, 512, 0, 0);
}

// Round 19
// 70.404 us; speedup vs baseline: 1.4176x; 1.0947x over previous
//
#include <hip/hip_runtime.h>
#include <hip/hip_bf16.h>

typedef __attribute__((ext_vector_type(8))) __bf16 bf16x8;
typedef __attribute__((ext_vector_type(8))) unsigned short ushort8;
typedef __attribute__((ext_vector_type(4))) float f32x4;

#define DEVFN static __device__ __forceinline__

constexpr int B_ = 4, N_ = 1024, H_ = 8, DH_ = 64, INNER_ = 512, QC_ = 1536;
constexpr int JS_ = 2;                            // attention j-split
constexpr float LA_ = 0.33f, LD_ = 0.33f, LG_ = 0.33f;
constexpr float SCALE2_ = 0.125f * 1.44269504088896f;   // 1/sqrt(64) * log2(e)
constexpr long OCP_STRIDE_ = (long)4096 * 512;   // per-js partial O (bf16 elems)
constexpr long LP_STRIDE_  = (long)4 * 8 * 1024; // per-js partial l (f32 elems)

DEVFN unsigned short f2b(float f){
  unsigned int u = __builtin_bit_cast(unsigned int, f);
  u += 0x7FFFu + ((u >> 16) & 1u);
  return (unsigned short)(u >> 16);
}
DEVFN float b2f(unsigned short s){
  unsigned int u = ((unsigned int)s) << 16;
  return __builtin_bit_cast(float, u);
}
DEVFN float fexp2(float x){   // 2^x, single v_exp_f32 (HW-interlocked)
  float r; asm("v_exp_f32 %0, %1" : "=v"(r) : "v"(x)); return r;
}
DEVFN unsigned int pack2(float lo, float hi){  // 2 x f32 -> packed bf16 (RNE)
  union { unsigned int u; __bf16 h[2]; } z;
  z.h[0] = (__bf16)lo; z.h[1] = (__bf16)hi;
  return z.u;
}

DEVFN f32x4 mfma16(bf16x8 a, bf16x8 b, f32x4 c){
  return __builtin_amdgcn_mfma_f32_16x16x32_bf16(a, b, c, 0, 0, 0);
}

DEVFN bf16x8 ldsb8(const unsigned short* p){ return *(const bf16x8*)p; }

// async global->LDS, 16B per lane; LDS dest is wave-uniform base + lane*16
DEVFN void gload16(const unsigned short* g, unsigned short* l){
  __builtin_amdgcn_global_load_lds(
      (const __attribute__((address_space(1))) unsigned int*)g,
      (__attribute__((address_space(3))) unsigned int*)l, 16, 0, 0);
}

// LDS-only workgroup barrier (no vmcnt drain).
DEVFN void lds_barrier(){
  __builtin_amdgcn_sched_barrier(0);
  asm volatile("s_waitcnt lgkmcnt(0)\n\ts_barrier" ::: "memory");
  __builtin_amdgcn_sched_barrier(0);
}

// LESSONS LOG:
//  r6: 64-lane same-address shared atomicAdd serializes ~64x (use __ballot).
//  r8: XCD block swizzle null/negative — working set is L3-resident.
//  r8: 256-block grids = 1 wave/SIMD leave every stall exposed (G1).
//  r10: padded LDS rows de-conflict; XOR on top re-conflicts. Pad OR swizzle.
//  r11/r12: barrier vmcnt-drain removal NEUTRAL — occupancy covers the drain.
//  r13: JS 2->4 regressed (fixed costs); r14: 2-deep reg prefetch NEUTRAL.
//  r15: QB=128 + kf-hoist WIN — 70.7us, session best.
//  r16: DMA dbuf LDS 27.6->41.2KB cut residency 5->3: REGRESSED.
//  r17: vf+mbv hoists under launch_bounds(256,3) SPILLED (+90MB traffic).
//  r18: mbv hoist alone -> VGPR 112 -> 4 blocks/CU: REGRESSED (77us).
//  => The attention structure balances at 5 blocks/CU with a LEAN live set;
//     every per-wave cache beyond kf trades residency at a net loss.
//  r19: verbatim reversion to r15 (measured optimum).

// wave-0 ballot-based mask-encoding detect. t<64 == wave 0 exactly.
DEVFN int detect_enc_w0(const unsigned char* m8, const int* m32, const float* mf,
                        int t, int* fsh){
  if (t < 64){
    unsigned char a = m8[t];
    int bb = m32[t];
    float c = mf[t];
    unsigned long long bad0 = __ballot(a > 1);
    unsigned long long one0 = __ballot(a == 1);
    unsigned long long bad1 = __ballot(bb != 0 && bb != 1);
    unsigned long long one1 = __ballot(bb == 1);
    unsigned long long bad2 = __ballot(c != 0.0f && c != 1.0f);
    unsigned long long one2 = __ballot(c == 1.0f);
    if (t == 0){
      int f = 0;
      if (bad0 == 0ull && __popcll(one0) > 42) f = 0;
      else if (bad1 == 0ull && __popcll(one1) > 42) f = 1;
      else if (bad2 == 0ull && __popcll(one2) > 42) f = 2;
      *fsh = f;
    }
  }
  __syncthreads();
  return *fsh;
}

// ---------- fused prep: mask | cvt x | transpose Wqkv | transpose Wout ----------
__global__ void prep_k(const unsigned char* __restrict__ m8, const int* __restrict__ m32,
                       const float* __restrict__ mf, unsigned char* __restrict__ mv,
                       const float* __restrict__ x, unsigned short* __restrict__ xb,
                       const float* __restrict__ Wq, unsigned short* __restrict__ WqT,
                       const float* __restrict__ Wo, unsigned short* __restrict__ WoT)
{
  const int bid = blockIdx.x, t = threadIdx.x;
  if (bid < 16){
    __shared__ int fsh;
    int f = detect_enc_w0(m8, m32, mf, t, &fsh);
    int i = bid * 256 + t;
    unsigned char v;
    if (f == 0) v = (m8[i] != 0);
    else if (f == 1) v = (m32[i] != 0);
    else v = (mf[i] != 0.0f);
    mv[i] = v;
  } else if (bid < 2064){
    int i = (bid - 16) * 256 + t;
    float4 v = ((const float4*)x)[i];
    ushort4 o = { f2b(v.x), f2b(v.y), f2b(v.z), f2b(v.w) };
    ((ushort4*)xb)[i] = o;
  } else {
    const float* W; unsigned short* Wt; int K, Nn, bx, by;
    if (bid < 2832){ W = Wq; Wt = WqT; K = 512; Nn = 1536; int r = bid - 2064; bx = r % 48; by = r / 48; }
    else           { W = Wo; Wt = WoT; K = 512; Nn = 512;  int r = bid - 2832; bx = r % 16; by = r / 16; }
    __shared__ float tt[32][33];
    int nb = bx * 32, kb = by * 32;
    int tx = t & 31, ty = t >> 5;
    #pragma unroll
    for (int i = 0; i < 32; i += 8)
      tt[ty + i][tx] = W[(long)(kb + ty + i) * Nn + nb + tx];
    __syncthreads();
    #pragma unroll
    for (int i = 0; i < 32; i += 8)
      Wt[(long)(nb + ty + i) * K + kb + tx] = f2b(tt[tx][ty + i]);
  }
}

// ---------- bf16 MFMA GEMM, 2-phase double-buffered + LDS XOR swizzle ----------
// MODE 0: Cout(bf16) = acc; V-columns additionally scattered into VtOut
// MODE 1: Cout(bf16) = acc + LA*(sum_js O_js)/(sum_js l_js)  (attn combine)
// MODE 2: Cout(f32)  = acc + Cin[col] (bias)
template<int MODE, int BM, int BN>
__global__ __launch_bounds__(256)
void gemm_bt_k(const unsigned short* __restrict__ A, const unsigned short* __restrict__ Bt,
               const float* __restrict__ Cin, void* __restrict__ Cout,
               const unsigned short* __restrict__ Op, const float* __restrict__ Lp,
               unsigned short* __restrict__ VtOut,
               int M, int Nn, int K, long azs, long bzs)
{
  constexpr int BK = 64;
  constexpr int WM = BM / 2, WN = BN / 2, MR = WM / 16, NR = WN / 16;
  __shared__ __attribute__((aligned(16))) unsigned short As[2][BM * BK];
  __shared__ __attribute__((aligned(16))) unsigned short Bs[2][BN * BK];
  const int bm = blockIdx.x * BM, bn = blockIdx.y * BN, z = blockIdx.z;
  const unsigned short* Ap = A + (long)z * azs;
  const unsigned short* Bp = Bt + (long)z * bzs;
  const int tid = threadIdx.x, w = tid >> 6, lane = tid & 63;
  const int l15 = lane & 15, lg = lane >> 4;
  const int wr = w >> 1, wc = w & 1;
  const int srow = lane >> 3;
  const int sk0 = ((lane & 7) ^ srow) * 8;            // pre-swizzled source chunk
  const int rk0 = (lg ^ (l15 & 7)) * 8;               // swizzled read slot, k<32
  const int rk1 = ((lg + 4) ^ (l15 & 7)) * 8;         // swizzled read slot, k>=32

  f32x4 acc[MR][NR] = {};

  for (int kk = 0;;){
    if (kk == 0){
      #pragma unroll
      for (int i = 0; i < BM / 32; i++){
        int r0 = i * 32 + w * 8;
        gload16(Ap + (long)(bm + r0 + srow) * K + sk0, &As[0][r0 * BK]);
      }
      #pragma unroll
      for (int i = 0; i < BN / 32; i++){
        int r0 = i * 32 + w * 8;
        gload16(Bp + (long)(bn + r0 + srow) * K + sk0, &Bs[0][r0 * BK]);
      }
      __syncthreads();   // drains vmcnt: tile0 visible (required for DMA)
    }
    int cur = (kk / BK) & 1;
    if (kk + BK < K){
      #pragma unroll
      for (int i = 0; i < BM / 32; i++){
        int r0 = i * 32 + w * 8;
        gload16(Ap + (long)(bm + r0 + srow) * K + (kk + BK) + sk0, &As[cur ^ 1][r0 * BK]);
      }
      #pragma unroll
      for (int i = 0; i < BN / 32; i++){
        int r0 = i * 32 + w * 8;
        gload16(Bp + (long)(bn + r0 + srow) * K + (kk + BK) + sk0, &Bs[cur ^ 1][r0 * BK]);
      }
    }
    bf16x8 af[MR][2], bf[NR][2];
    #pragma unroll
    for (int m = 0; m < MR; m++){
      const unsigned short* p = &As[cur][(wr * WM + m * 16 + l15) * BK];
      af[m][0] = ldsb8(p + rk0); af[m][1] = ldsb8(p + rk1);
    }
    #pragma unroll
    for (int n = 0; n < NR; n++){
      const unsigned short* p = &Bs[cur][(wc * WN + n * 16 + l15) * BK];
      bf[n][0] = ldsb8(p + rk0); bf[n][1] = ldsb8(p + rk1);
    }
    #pragma unroll
    for (int m = 0; m < MR; m++)
      #pragma unroll
      for (int n = 0; n < NR; n++){
        acc[m][n] = mfma16(af[m][0], bf[n][0], acc[m][n]);
        acc[m][n] = mfma16(af[m][1], bf[n][1], acc[m][n]);
      }
    kk += BK;
    if (kk >= K) break;
    __syncthreads();
  }

  #pragma unroll
  for (int m = 0; m < MR; m++)
    #pragma unroll
    for (int n = 0; n < NR; n++){
      int row0 = bm + wr * WM + m * 16 + lg * 4;
      int col = bn + wc * WN + n * 16 + l15;
      if (MODE == 0){
        ushort4 o;
        unsigned short* op = (unsigned short*)&o;
        #pragma unroll
        for (int r = 0; r < 4; r++){
          op[r] = f2b(acc[m][n][r]);
          ((unsigned short*)Cout)[(long)(row0 + r) * Nn + col] = op[r];
        }
        int hm = col % 192;
        if (hm >= 128){
          int bb = row0 >> 10, j0 = row0 & (N_ - 1);
          int hd = (col / 192) * 64 + (hm - 128);
          *(ushort4*)(VtOut + ((long)bb * INNER_ + hd) * N_ + j0) = o;
        }
      } else if (MODE == 1){
        #pragma unroll
        for (int r = 0; r < 4; r++){
          int row = row0 + r;
          float v = acc[m][n][r];
          long obase = ((long)z * N_ + row) * INNER_ + col;
          long lbase = ((long)z * H_ + (col >> 6)) * N_ + row;
          float o = 0.f, l = 0.f;
          #pragma unroll
          for (int js = 0; js < JS_; js++){
            o += b2f(Op[js * OCP_STRIDE_ + obase]);
            l += Lp[js * LP_STRIDE_ + lbase];
          }
          v += LA_ * o / l;
          ((unsigned short*)Cout)[((long)z * N_ + row) * Nn + col] = f2b(v);
        }
      } else {
        #pragma unroll
        for (int r = 0; r < 4; r++)
          ((float*)Cout)[(long)(row0 + r) * Nn + col] = acc[m][n][r] + Cin[col];
      }
    }
}

// ---------- fused: streaming attention partial | Madd build ----------
// blocks [0,512): attention (QB=128, 2 q-groups/wave, JS=2);
// blocks [512,4608): Madd (heterogeneous overlap — r9).
// Attention LDS: [64][72] padded rows, natural chunk indexing (r10 lesson).
__global__ __launch_bounds__(256, 3)
void attn_madd_k(const unsigned short* __restrict__ QKV, const unsigned short* __restrict__ Vt,
                 const unsigned char* __restrict__ mv,
                 unsigned short* __restrict__ Ocp, float* __restrict__ Lp,
                 const unsigned char* __restrict__ m8, const int* __restrict__ m32,
                 const float* __restrict__ mf,
                 const float* __restrict__ adj, const float* __restrict__ dist,
                 unsigned short* __restrict__ Madd)
{
  __shared__ __attribute__((aligned(16))) unsigned short Ks[64][72];      // [j][k]
  __shared__ __attribute__((aligned(16))) unsigned short Vs[64][72];      // [d][j]
  __shared__ __attribute__((aligned(16))) unsigned short Ps[4][16][72];   // [q][k]
  const int bid = blockIdx.x, tid = threadIdx.x;

  if (bid >= 512){
    // ---- Madd branch ----
    int f = detect_enc_w0(m8, m32, mf, tid, (int*)&Ps[0][0][0]);
    long i = (long)(bid - 512) * 256 + tid;
    long e = i * 4;
    int b = (int)(e >> 20);
    int rem = (int)(e & (long)(N_ * N_ - 1));
    int row = rem >> 10, col0 = rem & (N_ - 1);
    float4 a = ((const float4*)adj)[i];
    float4 d = ((const float4*)dist)[i];
    bool mi, mc[4];
    if (f == 0){
      mi = m8[b * N_ + row] != 0;
      unsigned int pk = *(const unsigned int*)(m8 + b * N_ + col0);
      #pragma unroll
      for (int r = 0; r < 4; r++) mc[r] = ((pk >> (8 * r)) & 255u) != 0;
    } else if (f == 1){
      mi = m32[b * N_ + row] != 0;
      #pragma unroll
      for (int r = 0; r < 4; r++) mc[r] = m32[b * N_ + col0 + r] != 0;
    } else {
      mi = mf[b * N_ + row] != 0.0f;
      #pragma unroll
      for (int r = 0; r < 4; r++) mc[r] = mf[b * N_ + col0 + r] != 0.0f;
    }
    float va[4] = {a.x, a.y, a.z, a.w};
    float vd[4] = {d.x, d.y, d.z, d.w};
    ushort4 o;
    unsigned short* op = (unsigned short*)&o;
    #pragma unroll
    for (int r = 0; r < 4; r++){
      bool m2 = mi && mc[r];
      float v = m2 ? (LG_ * va[r] + LD_ * __expf(-vd[r])) : 0.0f;
      op[r] = f2b(v);
    }
    ((ushort4*)Madd)[i] = o;
    return;
  }

  // ---- attention branch (swapped QK^T, no-max softmax, QB=128, JS=2) ----
  const int qb = (bid & 7) * 128, h = (bid >> 3) & 7;
  const int zc = bid >> 6;                // [0, 4*JS_)
  const int b = zc & 3, js = zc >> 2;     // js in [0, JS_)
  const int w = tid >> 6, lane = tid & 63;
  const int l15 = lane & 15, lg = lane >> 4;

  // two q-groups per wave: rows qb + w*32 + qg*16 + l15
  bf16x8 qf[2][2];
  bool rv[2];
  #pragma unroll
  for (int qg = 0; qg < 2; qg++){
    const long qr = (long)(b * N_ + qb + w * 32 + qg * 16 + l15) * QC_ + h * 192;
    qf[qg][0] = *(const bf16x8*)(QKV + qr + lg * 8);
    qf[qg][1] = *(const bf16x8*)(QKV + qr + 32 + lg * 8);
    rv[qg] = mv[b * N_ + qb + w * 32 + qg * 16 + l15] != 0;
  }

  float l_run[2] = {0.f, 0.f};
  f32x4 acc[2][4] = {};

  const unsigned short* Vbase = Vt + ((long)b * INNER_ + h * DH_) * N_;
  const unsigned short* Kbase = QKV + (long)b * N_ * QC_ + h * 192 + 64;
  const int kr0 = tid >> 3, kr1 = kr0 + 32;
  const int ko = (tid & 7) * 8;                  // natural chunk (write & global)
  const int jb0 = js * (N_ / JS_);
  constexpr int NT = N_ / JS_ / 64;              // j-tiles per block (8 at JS=2)

  // prologue: load tile 0 into registers (T14 issue-early/write-late)
  ushort8 kreg0, kreg1, vreg0, vreg1;
  {
    kreg0 = *(const ushort8*)(Kbase + (long)(jb0 + kr0) * QC_ + ko);
    kreg1 = *(const ushort8*)(Kbase + (long)(jb0 + kr1) * QC_ + ko);
    vreg0 = *(const ushort8*)(Vbase + (long)kr0 * N_ + jb0 + ko);
    vreg1 = *(const ushort8*)(Vbase + (long)kr1 * N_ + jb0 + ko);
  }

  for (int jt = 0; jt < NT; jt++){
    const int jbase = jb0 + jt * 64;
    lds_barrier();                        // prev iter's LDS reads complete
    *(ushort8*)&Ks[kr0][ko] = kreg0;
    *(ushort8*)&Ks[kr1][ko] = kreg1;
    *(ushort8*)&Vs[kr0][ko] = vreg0;
    *(ushort8*)&Vs[kr1][ko] = vreg1;
    if (jt < NT - 1){
      const int jn = jbase + 64;
      kreg0 = *(const ushort8*)(Kbase + (long)(jn + kr0) * QC_ + ko);
      kreg1 = *(const ushort8*)(Kbase + (long)(jn + kr1) * QC_ + ko);
      vreg0 = *(const ushort8*)(Vbase + (long)kr0 * N_ + jn + ko);
      vreg1 = *(const ushort8*)(Vbase + (long)kr1 * N_ + jn + ko);
    }
    lds_barrier();                        // K/V tile visible

    // hoist K fragments + masks once per tile (reused by both q-groups)
    bf16x8 kf[4][2];
    #pragma unroll
    for (int ct = 0; ct < 4; ct++){
      kf[ct][0] = ldsb8(&Ks[ct * 16 + l15][lg * 8]);
      kf[ct][1] = ldsb8(&Ks[ct * 16 + l15][32 + lg * 8]);
    }
    unsigned int cvm[4];
    #pragma unroll
    for (int ct = 0; ct < 4; ct++)
      cvm[ct] = *(const unsigned int*)(mv + b * N_ + jbase + ct * 16 + lg * 4);

    #pragma unroll
    for (int qg = 0; qg < 2; qg++){
      // S^T = K Q^T : lane holds key = ct*16 + lg*4 + r, q = l15
      f32x4 s[4];
      __builtin_amdgcn_s_setprio(1);
      #pragma unroll
      for (int ct = 0; ct < 4; ct++){
        f32x4 zz = {};
        zz = mfma16(kf[ct][0], qf[qg][0], zz);
        zz = mfma16(kf[ct][1], qf[qg][1], zz);
        s[ct] = zz;
      }
      __builtin_amdgcn_s_setprio(0);

      // no-max softmax in base-2; invalid row -> 0; invalid key -> -3e38 -> 0
      float tsum = 0.f;
      unsigned int pw[4][2];
      #pragma unroll
      for (int ct = 0; ct < 4; ct++){
        float pv[4];
        #pragma unroll
        for (int r = 0; r < 4; r++){
          float xx = s[ct][r] * SCALE2_;
          bool ck = ((cvm[ct] >> (8 * r)) & 255u) != 0;
          float sv = ck ? xx : -3e38f;
          if (!rv[qg]) sv = 0.0f;
          float pp = fexp2(sv);
          tsum += pp;
          pv[r] = pp;
        }
        pw[ct][0] = pack2(pv[0], pv[1]);
        pw[ct][1] = pack2(pv[2], pv[3]);
      }
      tsum += __shfl_xor(tsum, 16);
      tsum += __shfl_xor(tsum, 32);
      l_run[qg] += tsum;

      // Ps is reused across qg: wave-local wait ensures prior reads landed
      asm volatile("s_waitcnt lgkmcnt(0)" ::: "memory");
      __builtin_amdgcn_sched_barrier(0);
      #pragma unroll
      for (int ct = 0; ct < 4; ct++)
        #pragma unroll
        for (int p2 = 0; p2 < 2; p2++){
          int klo = ct * 16 + lg * 4 + 2 * p2;
          *(unsigned int*)&Ps[w][l15][klo] = pw[ct][p2];
        }
      asm volatile("s_waitcnt lgkmcnt(0)" ::: "memory");
      __builtin_amdgcn_sched_barrier(0);

      bf16x8 pf0 = ldsb8(&Ps[w][l15][lg * 8]);
      bf16x8 pf1 = ldsb8(&Ps[w][l15][32 + lg * 8]);
      __builtin_amdgcn_s_setprio(1);
      #pragma unroll
      for (int ct = 0; ct < 4; ct++){
        bf16x8 v0 = ldsb8(&Vs[ct * 16 + l15][lg * 8]);
        bf16x8 v1 = ldsb8(&Vs[ct * 16 + l15][32 + lg * 8]);
        acc[qg][ct] = mfma16(pf0, v0, acc[qg][ct]);
        acc[qg][ct] = mfma16(pf1, v1, acc[qg][ct]);
      }
      __builtin_amdgcn_s_setprio(0);
    }
  }

  // write unnormalized partial O (bf16) and partial l (f32)
  #pragma unroll
  for (int qg = 0; qg < 2; qg++){
    #pragma unroll
    for (int r = 0; r < 4; r++){
      long orow = (long)js * (OCP_STRIDE_ / INNER_) + b * N_ + qb + w * 32 + qg * 16 + lg * 4 + r;
      #pragma unroll
      for (int ct = 0; ct < 4; ct++)
        Ocp[orow * INNER_ + h * DH_ + ct * 16 + l15] = f2b(acc[qg][ct][r]);
    }
    if (lg == 0)
      Lp[(long)js * LP_STRIDE_ + ((long)b * H_ + h) * N_ + qb + w * 32 + qg * 16 + l15] = l_run[qg];
  }
}

extern "C" void kernel_launch(void* const* d_in, const int* in_sizes, int n_in,
                              void* d_out, int out_size, void* d_ws, size_t ws_size,
                              hipStream_t stream)
{
  const float* x    = (const float*)d_in[0];
  const void*  msk  = d_in[1];
  const float* adj  = (const float*)d_in[2];
  const float* dst  = (const float*)d_in[3];
  const float* wqkv = (const float*)d_in[4];
  const float* wout = (const float*)d_in[5];
  const float* bout = (const float*)d_in[6];
  float* out = (float*)d_out;

  char* p = (char*)d_ws;
  unsigned short* QKV  = (unsigned short*)p;  p += (long)4096 * 1536 * 2;
  unsigned short* Xb   = (unsigned short*)p;  p += (long)4096 * 512 * 2;
  unsigned short* WqT  = (unsigned short*)p;  p += (long)1536 * 512 * 2;
  unsigned short* WoT  = (unsigned short*)p;  p += (long)512 * 512 * 2;
  unsigned short* Vt   = (unsigned short*)p;  p += (long)4 * 512 * 1024 * 2;
  unsigned short* Madd = (unsigned short*)p;  p += (long)4 * 1024 * 1024 * 2;
  unsigned short* Ocp  = (unsigned short*)p;  p += (long)JS_ * OCP_STRIDE_ * 2;
  float*          Lp   = (float*)p;           p += (long)JS_ * LP_STRIDE_ * 4;
  unsigned short* OcB  = (unsigned short*)p;  p += (long)4096 * 512 * 2;
  unsigned char*  mv   = (unsigned char*)p;   p += 4096;

  prep_k<<<3088, 256, 0, stream>>>((const unsigned char*)msk, (const int*)msk,
                                   (const float*)msk, mv, x, Xb, wqkv, WqT, wout, WoT);
  gemm_bt_k<0, 128, 64><<<dim3(32, 24, 1), 256, 0, stream>>>(
      Xb, WqT, nullptr, QKV, nullptr, nullptr, Vt, 4096, 1536, 512, 0, 0);
  attn_madd_k<<<4608, 256, 0, stream>>>(QKV, Vt, mv, Ocp, Lp,
                                        (const unsigned char*)msk, (const int*)msk,
                                        (const float*)msk, adj, dst, Madd);
  gemm_bt_k<1, 64, 64><<<dim3(16, 8, 4), 256, 0, stream>>>(
      Madd, Vt, nullptr, OcB, Ocp, Lp, nullptr, 1024, 512, 1024,
      (long)1024 * 1024, (long)512 * 1024);
  gemm_bt_k<2, 64, 64><<<dim3(64, 8, 1), 256, 0, stream>>>(
      OcB, WoT, bout, out, nullptr, nullptr, nullptr, 4096, 512, 512, 0, 0);
}